// Round 1
// baseline (730.510 us; speedup 1.0000x reference)
//
#include <hip/hip_runtime.h>
#include <hip/hip_bf16.h>
#include <cstdint>
#include <cstddef>

#define NB_B 8
#define NB_N 2048
#define NB_C 128
#define NB_H 4
#define NB_D 32
#define NB_S1 3
#define NB_K 16
#define NB_KT 48
#define INV_SQRT_D 0.17677669529663688f

// ---------------------------------------------------------------------------
// prep: sq[b,n] = |coord|^2  and  WkT[i][col][c] = Wk[i][c][col]
// ---------------------------------------------------------------------------
__global__ __launch_bounds__(256) void prep_kernel(const float* __restrict__ coord,
                                                   const float* __restrict__ Wk,
                                                   float* __restrict__ sq,
                                                   float* __restrict__ wkT) {
  int tid = blockIdx.x * 256 + threadIdx.x;
  if (tid < NB_B * NB_N) {
    float x = coord[tid * 3 + 0], y = coord[tid * 3 + 1], z = coord[tid * 3 + 2];
    sq[tid] = x * x + y * y + z * z;
  }
  if (tid < NB_S1 * NB_C * NB_C) {
    int i = tid >> 14;          // / 16384
    int rem = tid & 16383;
    int col = rem >> 7, c = rem & 127;
    wkT[tid] = Wk[i * 16384 + c * 128 + col];
  }
}

// ---------------------------------------------------------------------------
// topk: per point, 48 nearest neighbors in (dist, idx) ascending order
// (matches jax.lax.top_k(-dist, 48) ordering incl. tie-break by lower index)
// ---------------------------------------------------------------------------
__global__ __launch_bounds__(256) void topk_kernel(const float* __restrict__ coord,
                                                   const float* __restrict__ sq,
                                                   int* __restrict__ idx_out) {
  __shared__ unsigned long long wmin[2][4];
  const int bn = blockIdx.x;
  const int b = bn >> 11, n = bn & 2047;
  const float* cb = coord + (size_t)b * NB_N * 3;
  const float* sqb = sq + b * NB_N;
  const int t = threadIdx.x;
  const int w = t >> 6, l = t & 63;

  const float cx = cb[n * 3 + 0], cy = cb[n * 3 + 1], cz = cb[n * 3 + 2];
  const float sqn = sqb[n];

  unsigned long long cand[8];
#pragma unroll
  for (int it = 0; it < 8; ++it) {
    int m = it * 256 + t;
    float mx = cb[m * 3 + 0], my = cb[m * 3 + 1], mz = cb[m * 3 + 2];
    float d = sqn + sqb[m] - 2.f * (cx * mx + cy * my + cz * mz);
    unsigned int db = __float_as_uint(d);
    // monotonic float->uint mapping (handles tiny negatives from rounding)
    unsigned int key = (db & 0x80000000u) ? ~db : (db | 0x80000000u);
    cand[it] = ((unsigned long long)key << 32) | (unsigned int)m;
  }

  // Batcher odd-even merge sort, 8 elements ascending, static indices only
#define CE(a, b)                                              \
  {                                                           \
    if (cand[a] > cand[b]) {                                  \
      unsigned long long tmp_ = cand[a];                      \
      cand[a] = cand[b];                                      \
      cand[b] = tmp_;                                         \
    }                                                         \
  }
  CE(0, 1) CE(2, 3) CE(4, 5) CE(6, 7)
  CE(0, 2) CE(1, 3) CE(4, 6) CE(5, 7)
  CE(1, 2) CE(5, 6)
  CE(0, 4) CE(1, 5) CE(2, 6) CE(3, 7)
  CE(2, 4) CE(3, 5)
  CE(1, 2) CE(3, 4) CE(5, 6)
#undef CE

  for (int r = 0; r < NB_KT; ++r) {
    unsigned long long v = cand[0];
#pragma unroll
    for (int off = 1; off < 64; off <<= 1) {
      unsigned long long o = __shfl_xor(v, off);
      if (o < v) v = o;
    }
    if (l == 0) wmin[r & 1][w] = v;
    __syncthreads();
    unsigned long long g0 = wmin[r & 1][0], g1 = wmin[r & 1][1];
    unsigned long long g2 = wmin[r & 1][2], g3 = wmin[r & 1][3];
    unsigned long long ga = g0 < g1 ? g0 : g1;
    unsigned long long gb = g2 < g3 ? g2 : g3;
    unsigned long long g = ga < gb ? ga : gb;
    if (t == 0) idx_out[(size_t)bn * NB_KT + r] = (int)(unsigned int)(g & 0xFFFFFFFFu);
    if (cand[0] == g) {  // unique winner (index embedded in key)
      cand[0] = cand[1]; cand[1] = cand[2]; cand[2] = cand[3]; cand[3] = cand[4];
      cand[4] = cand[5]; cand[5] = cand[6]; cand[6] = cand[7]; cand[7] = ~0ULL;
    }
  }
}

// ---------------------------------------------------------------------------
// main fused kernel: 4 waves/block, 2 points/wave (8 points/block)
// lane layout for u/logits phases: h_l = l>>4 (head), cg = l&15 (c-group of 8)
// ---------------------------------------------------------------------------
__global__ __launch_bounds__(256) void main_kernel(
    const float* __restrict__ pcd,
    const float* __restrict__ Wq, const float* __restrict__ bq,
    const float* __restrict__ bk,
    const float* __restrict__ Wv, const float* __restrict__ bv,
    const float* __restrict__ wkT,
    const int* __restrict__ nbr_idx,
    float* __restrict__ out) {
  __shared__ __align__(16) float self_lds[8][128];
  __shared__ float q_lds[8][4 * 33];  // padded per-head rows: bank-conflict-free broadcast
  __shared__ __align__(16) float nbr_lds[4][128];
  __shared__ float qbk_lds[8][12];

  const int t = threadIdx.x;
  const int w = t >> 6, l = t & 63;
  const int slot0 = w * 2, slot1 = w * 2 + 1;
  const int pt0 = blockIdx.x * 8 + slot0;
  const int pt1 = pt0 + 1;

  // ---- stage self rows (float2 per lane: elems 2l, 2l+1) ----
  {
    float2 s0 = reinterpret_cast<const float2*>(pcd + (size_t)pt0 * 128)[l];
    float2 s1 = reinterpret_cast<const float2*>(pcd + (size_t)pt1 * 128)[l];
    reinterpret_cast<float2*>(&self_lds[slot0][0])[l] = s0;
    reinterpret_cast<float2*>(&self_lds[slot1][0])[l] = s1;
  }
  __syncthreads();

  // ---- q, v matvec: lane owns output cols 2l, 2l+1 ----
  float q0a = 0, q0b = 0, q1a = 0, q1b = 0;
  float v0a = 0, v0b = 0, v1a = 0, v1b = 0;
#pragma unroll 4
  for (int c = 0; c < 128; ++c) {
    float2 wq = reinterpret_cast<const float2*>(Wq + c * 128)[l];
    float2 wv = reinterpret_cast<const float2*>(Wv + c * 128)[l];
    float x0 = self_lds[slot0][c];
    float x1 = self_lds[slot1][c];
    q0a = fmaf(wq.x, x0, q0a); q0b = fmaf(wq.y, x0, q0b);
    q1a = fmaf(wq.x, x1, q1a); q1b = fmaf(wq.y, x1, q1b);
    v0a = fmaf(wv.x, x0, v0a); v0b = fmaf(wv.y, x0, v0b);
    v1a = fmaf(wv.x, x1, v1a); v1b = fmaf(wv.y, x1, v1b);
  }
  {
    float2 bqv = reinterpret_cast<const float2*>(bq)[l];
    float2 bvv = reinterpret_cast<const float2*>(bv)[l];
    q0a += bqv.x; q0b += bqv.y; q1a += bqv.x; q1b += bqv.y;
    v0a += bvv.x; v0b += bvv.y; v1a += bvv.x; v1b += bvv.y;
  }
  {
    int h = l >> 4;           // (2l)>>5
    int d = (2 * l) & 31;
    q_lds[slot0][h * 33 + d] = q0a;
    q_lds[slot0][h * 33 + d + 1] = q0b;
    q_lds[slot1][h * 33 + d] = q1a;
    q_lds[slot1][h * 33 + d + 1] = q1b;
  }
  __syncthreads();

  // ---- qbk[p][i][h] = q[h,:] . bk[i][h*32:...] ----
  if (l < 24) {
    int p = l / 12, g = l % 12;
    int i = g >> 2, h = g & 3;
    int slot = w * 2 + p;
    const float* qp = &q_lds[slot][h * 33];
    const float* bkp = bk + i * 128 + h * 32;
    float s = 0.f;
#pragma unroll 8
    for (int d = 0; d < 32; ++d) s = fmaf(qp[d], bkp[d], s);
    qbk_lds[slot][g] = s;
  }

  // ---- u[p][i][k] = sum_d WkT[i][h_l*32+d][cg*8+k] * q_p[h_l,d] ----
  const int h_l = l >> 4, cg = l & 15;
  float u[2][3][8];
#pragma unroll
  for (int p = 0; p < 2; ++p)
#pragma unroll
    for (int i = 0; i < 3; ++i)
#pragma unroll
      for (int k = 0; k < 8; ++k) u[p][i][k] = 0.f;
  {
    const float* q0p = &q_lds[slot0][h_l * 33];
    const float* q1p = &q_lds[slot1][h_l * 33];
#pragma unroll
    for (int i = 0; i < 3; ++i) {
      const float* wbase = wkT + ((i * 128 + h_l * 32) * 128) + cg * 8;
#pragma unroll 8
      for (int d = 0; d < 32; ++d) {
        float4 wa = *reinterpret_cast<const float4*>(wbase + d * 128);
        float4 wb = *reinterpret_cast<const float4*>(wbase + d * 128 + 4);
        float qv0 = q0p[d], qv1 = q1p[d];
        u[0][i][0] = fmaf(wa.x, qv0, u[0][i][0]);
        u[0][i][1] = fmaf(wa.y, qv0, u[0][i][1]);
        u[0][i][2] = fmaf(wa.z, qv0, u[0][i][2]);
        u[0][i][3] = fmaf(wa.w, qv0, u[0][i][3]);
        u[0][i][4] = fmaf(wb.x, qv0, u[0][i][4]);
        u[0][i][5] = fmaf(wb.y, qv0, u[0][i][5]);
        u[0][i][6] = fmaf(wb.z, qv0, u[0][i][6]);
        u[0][i][7] = fmaf(wb.w, qv0, u[0][i][7]);
        u[1][i][0] = fmaf(wa.x, qv1, u[1][i][0]);
        u[1][i][1] = fmaf(wa.y, qv1, u[1][i][1]);
        u[1][i][2] = fmaf(wa.z, qv1, u[1][i][2]);
        u[1][i][3] = fmaf(wa.w, qv1, u[1][i][3]);
        u[1][i][4] = fmaf(wb.x, qv1, u[1][i][4]);
        u[1][i][5] = fmaf(wb.y, qv1, u[1][i][5]);
        u[1][i][6] = fmaf(wb.z, qv1, u[1][i][6]);
        u[1][i][7] = fmaf(wb.w, qv1, u[1][i][7]);
      }
    }
  }
  __syncthreads();

  // ---- logits + softmax, per point ----
  int nidx0 = (l < 48) ? nbr_idx[(size_t)pt0 * NB_KT + l] : 0;
  int nidx1 = (l < 48) ? nbr_idx[(size_t)pt1 * NB_KT + l] : 0;

  float am_p[2];
#pragma unroll
  for (int p = 0; p < 2; ++p) {
    const int pt = (p == 0) ? pt0 : pt1;
    const int slot = (p == 0) ? slot0 : slot1;
    const int nidx = (p == 0) ? nidx0 : nidx1;
    const float* pcd_b = pcd + (size_t)(pt >> 11) * NB_N * 128;
    float4 sA = *reinterpret_cast<const float4*>(&self_lds[slot][cg * 8]);
    float4 sB = *reinterpret_cast<const float4*>(&self_lds[slot][cg * 8 + 4]);

    int nb0 = __shfl(nidx, 0);
    float2 pre = reinterpret_cast<const float2*>(pcd_b + (size_t)nb0 * 128)[l];

    float lj[3];
#pragma unroll
    for (int i = 0; i < 3; ++i) {
      float qbk_ih = qbk_lds[slot][i * 4 + h_l];
      float myl = 0.f;
      for (int jj = 0; jj < 16; ++jj) {
        int j = i * 16 + jj;
        float2 cur = pre;
        if (j < 47) {  // software-pipeline: prefetch next neighbor row
          int nbn = __shfl(nidx, j + 1);
          pre = reinterpret_cast<const float2*>(pcd_b + (size_t)nbn * 128)[l];
        }
        reinterpret_cast<float2*>(&nbr_lds[w][0])[l] = cur;
        asm volatile("s_waitcnt lgkmcnt(0)" ::: "memory");
        float4 nA = *reinterpret_cast<const float4*>(&nbr_lds[w][cg * 8]);
        float4 nB = *reinterpret_cast<const float4*>(&nbr_lds[w][cg * 8 + 4]);
        float pl;
        pl =      (nA.x - sA.x) * u[p][i][0];
        pl = fmaf((nA.y - sA.y), u[p][i][1], pl);
        pl = fmaf((nA.z - sA.z), u[p][i][2], pl);
        pl = fmaf((nA.w - sA.w), u[p][i][3], pl);
        pl = fmaf((nB.x - sB.x), u[p][i][4], pl);
        pl = fmaf((nB.y - sB.y), u[p][i][5], pl);
        pl = fmaf((nB.z - sB.z), u[p][i][6], pl);
        pl = fmaf((nB.w - sB.w), u[p][i][7], pl);
        // reduce over the 16 lanes of this head-group
        pl += __shfl_xor(pl, 1);
        pl += __shfl_xor(pl, 2);
        pl += __shfl_xor(pl, 4);
        pl += __shfl_xor(pl, 8);
        float lg = (pl + qbk_ih) * INV_SQRT_D;
        if (jj == cg) myl = lg;  // lane cg keeps neighbor j = i*16+cg
      }
      lj[i] = myl;
    }
    // softmax per (i, head-group) across 16 lanes; attn = sum_i sum_k a*logit
    float am = 0.f;
#pragma unroll
    for (int i = 0; i < 3; ++i) {
      float m = lj[i];
      m = fmaxf(m, __shfl_xor(m, 1));
      m = fmaxf(m, __shfl_xor(m, 2));
      m = fmaxf(m, __shfl_xor(m, 4));
      m = fmaxf(m, __shfl_xor(m, 8));
      float e = expf(lj[i] - m);
      float se = e, swl = e * lj[i];
      se += __shfl_xor(se, 1); swl += __shfl_xor(swl, 1);
      se += __shfl_xor(se, 2); swl += __shfl_xor(swl, 2);
      se += __shfl_xor(se, 4); swl += __shfl_xor(swl, 4);
      se += __shfl_xor(se, 8); swl += __shfl_xor(swl, 8);
      am += swl / se;
    }
    am_p[p] = am;  // valid for head h_l on every lane of the group
  }

  // ---- epilogue: out[pt, 2l + {0,1}] = attn[h_l] * v ----
  {
    float2 o0 = make_float2(am_p[0] * v0a, am_p[0] * v0b);
    float2 o1 = make_float2(am_p[1] * v1a, am_p[1] * v1b);
    reinterpret_cast<float2*>(out + (size_t)pt0 * 128)[l] = o0;
    reinterpret_cast<float2*>(out + (size_t)pt1 * 128)[l] = o1;
  }
}

// ---------------------------------------------------------------------------
extern "C" void kernel_launch(void* const* d_in, const int* in_sizes, int n_in,
                              void* d_out, int out_size, void* d_ws, size_t ws_size,
                              hipStream_t stream) {
  const float* pcd   = (const float*)d_in[0];
  const float* coord = (const float*)d_in[1];
  // d_in[2] = K (scalar int, fixed 16 — hardcoded)
  const float* Wq = (const float*)d_in[3];
  const float* bq = (const float*)d_in[4];
  const float* Wk = (const float*)d_in[5];
  const float* bk = (const float*)d_in[6];
  const float* Wv = (const float*)d_in[7];
  const float* bv = (const float*)d_in[8];
  float* out = (float*)d_out;

  // workspace layout
  int*   idx_ws = (int*)d_ws;                                   // 16384*48*4 = 3,145,728 B
  float* sq_ws  = (float*)((char*)d_ws + 3145728);              // 65,536 B
  float* wkT_ws = (float*)((char*)d_ws + 3211264);              // 196,608 B (32B-aligned)

  prep_kernel<<<192, 256, 0, stream>>>(coord, Wk, sq_ws, wkT_ws);
  topk_kernel<<<NB_B * NB_N, 256, 0, stream>>>(coord, sq_ws, idx_ws);
  main_kernel<<<NB_B * NB_N / 8, 256, 0, stream>>>(pcd, Wq, bq, bk, Wv, bv,
                                                   wkT_ws, idx_ws, out);
}

// Round 2
// 439.310 us; speedup vs baseline: 1.6629x; 1.6629x over previous
//
#include <hip/hip_runtime.h>
#include <hip/hip_bf16.h>
#include <cstdint>
#include <cstddef>

#define NB_B 8
#define NB_N 2048
#define NB_C 128
#define NB_H 4
#define NB_D 32
#define NB_S1 3
#define NB_K 16
#define NB_KT 48
#define INV_SQRT_D 0.17677669529663688f

// ---------------------------------------------------------------------------
// prep: sq[b,n] = |coord|^2  and  WkT[i][col][c] = Wk[i][c][col]
// ---------------------------------------------------------------------------
__global__ __launch_bounds__(256) void prep_kernel(const float* __restrict__ coord,
                                                   const float* __restrict__ Wk,
                                                   float* __restrict__ sq,
                                                   float* __restrict__ wkT) {
  int tid = blockIdx.x * 256 + threadIdx.x;
  if (tid < NB_B * NB_N) {
    float x = coord[tid * 3 + 0], y = coord[tid * 3 + 1], z = coord[tid * 3 + 2];
    sq[tid] = x * x + y * y + z * z;
  }
  if (tid < NB_S1 * NB_C * NB_C) {
    int i = tid >> 14;          // / 16384
    int rem = tid & 16383;
    int col = rem >> 7, c = rem & 127;
    wkT[tid] = Wk[i * 16384 + c * 128 + col];
  }
}

// ---------------------------------------------------------------------------
// topk2: ONE WAVE per point. 64 lanes x 32 candidates. No LDS, no barriers.
// Each lane: 4 sorted-8 lists (Batcher-8, static indices). 48 extraction
// rounds: u64 butterfly min across wave; winning lane pops its list.
// Key = (monotonic_u32(dist) << 32) | idx  => exact (dist, idx) ascending,
// matching jax.lax.top_k(-dist, 48) incl. tie-break by lower index.
// ---------------------------------------------------------------------------
__global__ __launch_bounds__(256) void topk2_kernel(const float* __restrict__ coord,
                                                    const float* __restrict__ sq,
                                                    int* __restrict__ idx_out) {
  const int t = threadIdx.x;
  const int w = t >> 6, l = t & 63;
  const int bn = blockIdx.x * 4 + w;          // one wave per point
  const int b = bn >> 11, n = bn & 2047;
  const float* cb = coord + (size_t)b * NB_N * 3;
  const float* sqb = sq + b * NB_N;

  const float cx = cb[n * 3 + 0], cy = cb[n * 3 + 1], cz = cb[n * 3 + 2];
  const float sqn = sqb[n];

  // ---- distance phase: 32 candidates per lane, m = 64*i + l ----
  unsigned long long c0[8], c1[8], c2[8], c3[8];
#define DIST_KEY(dst, it)                                                     \
  {                                                                           \
    int m = (it) * 64 + l;                                                    \
    float mx = cb[m * 3 + 0], my = cb[m * 3 + 1], mz = cb[m * 3 + 2];         \
    float d = sqn + sqb[m] - 2.f * (cx * mx + cy * my + cz * mz);             \
    unsigned int db = __float_as_uint(d);                                     \
    unsigned int key = (db & 0x80000000u) ? ~db : (db | 0x80000000u);         \
    dst = ((unsigned long long)key << 32) | (unsigned int)m;                  \
  }
#pragma unroll
  for (int it = 0; it < 8; ++it) DIST_KEY(c0[it], it)
#pragma unroll
  for (int it = 0; it < 8; ++it) DIST_KEY(c1[it], 8 + it)
#pragma unroll
  for (int it = 0; it < 8; ++it) DIST_KEY(c2[it], 16 + it)
#pragma unroll
  for (int it = 0; it < 8; ++it) DIST_KEY(c3[it], 24 + it)
#undef DIST_KEY

  // ---- sort each list of 8 ascending (Batcher odd-even merge sort, 19 CE) --
#define CE(A, a, b)                                           \
  {                                                           \
    if (A[a] > A[b]) {                                        \
      unsigned long long tmp_ = A[a];                         \
      A[a] = A[b];                                            \
      A[b] = tmp_;                                            \
    }                                                         \
  }
#define SORT8(A)                                              \
  CE(A, 0, 1) CE(A, 2, 3) CE(A, 4, 5) CE(A, 6, 7)             \
  CE(A, 0, 2) CE(A, 1, 3) CE(A, 4, 6) CE(A, 5, 7)             \
  CE(A, 1, 2) CE(A, 5, 6)                                     \
  CE(A, 0, 4) CE(A, 1, 5) CE(A, 2, 6) CE(A, 3, 7)             \
  CE(A, 2, 4) CE(A, 3, 5)                                     \
  CE(A, 1, 2) CE(A, 3, 4) CE(A, 5, 6)
  SORT8(c0) SORT8(c1) SORT8(c2) SORT8(c3)
#undef SORT8
#undef CE

#define POP(A)                                                \
  {                                                           \
    A[0] = A[1]; A[1] = A[2]; A[2] = A[3]; A[3] = A[4];       \
    A[4] = A[5]; A[5] = A[6]; A[6] = A[7]; A[7] = ~0ULL;      \
  }

  unsigned long long lm;
  {
    unsigned long long a = c0[0] < c1[0] ? c0[0] : c1[0];
    unsigned long long b2 = c2[0] < c3[0] ? c2[0] : c3[0];
    lm = a < b2 ? a : b2;
  }

  unsigned int my_out = 0;
  for (int r = 0; r < NB_KT; ++r) {
    // wave-wide min butterfly: all lanes converge to global min g
    unsigned long long g = lm;
#pragma unroll
    for (int off = 1; off < 64; off <<= 1) {
      unsigned long long o = __shfl_xor(g, off);
      if (o < g) g = o;
    }
    if (l == r) my_out = (unsigned int)g;   // lane r keeps round-r winner idx
    if (lm == g) {                          // unique winning lane pops
      if (c0[0] == g) { POP(c0) }
      else if (c1[0] == g) { POP(c1) }
      else if (c2[0] == g) { POP(c2) }
      else { POP(c3) }
      unsigned long long a = c0[0] < c1[0] ? c0[0] : c1[0];
      unsigned long long b2 = c2[0] < c3[0] ? c2[0] : c3[0];
      lm = a < b2 ? a : b2;
    }
  }
#undef POP

  if (l < NB_KT) idx_out[(size_t)bn * NB_KT + l] = (int)my_out;
}

// ---------------------------------------------------------------------------
// main fused kernel: 4 waves/block, 2 points/wave (8 points/block)
// lane layout for u/logits phases: h_l = l>>4 (head), cg = l&15 (c-group of 8)
// ---------------------------------------------------------------------------
__global__ __launch_bounds__(256) void main_kernel(
    const float* __restrict__ pcd,
    const float* __restrict__ Wq, const float* __restrict__ bq,
    const float* __restrict__ bk,
    const float* __restrict__ Wv, const float* __restrict__ bv,
    const float* __restrict__ wkT,
    const int* __restrict__ nbr_idx,
    float* __restrict__ out) {
  __shared__ __align__(16) float self_lds[8][128];
  __shared__ float q_lds[8][4 * 33];  // padded per-head rows: bank-conflict-free broadcast
  __shared__ __align__(16) float nbr_lds[4][128];
  __shared__ float qbk_lds[8][12];

  const int t = threadIdx.x;
  const int w = t >> 6, l = t & 63;
  const int slot0 = w * 2, slot1 = w * 2 + 1;
  const int pt0 = blockIdx.x * 8 + slot0;
  const int pt1 = pt0 + 1;

  // ---- stage self rows (float2 per lane: elems 2l, 2l+1) ----
  {
    float2 s0 = reinterpret_cast<const float2*>(pcd + (size_t)pt0 * 128)[l];
    float2 s1 = reinterpret_cast<const float2*>(pcd + (size_t)pt1 * 128)[l];
    reinterpret_cast<float2*>(&self_lds[slot0][0])[l] = s0;
    reinterpret_cast<float2*>(&self_lds[slot1][0])[l] = s1;
  }
  __syncthreads();

  // ---- q, v matvec: lane owns output cols 2l, 2l+1 ----
  float q0a = 0, q0b = 0, q1a = 0, q1b = 0;
  float v0a = 0, v0b = 0, v1a = 0, v1b = 0;
#pragma unroll 4
  for (int c = 0; c < 128; ++c) {
    float2 wq = reinterpret_cast<const float2*>(Wq + c * 128)[l];
    float2 wv = reinterpret_cast<const float2*>(Wv + c * 128)[l];
    float x0 = self_lds[slot0][c];
    float x1 = self_lds[slot1][c];
    q0a = fmaf(wq.x, x0, q0a); q0b = fmaf(wq.y, x0, q0b);
    q1a = fmaf(wq.x, x1, q1a); q1b = fmaf(wq.y, x1, q1b);
    v0a = fmaf(wv.x, x0, v0a); v0b = fmaf(wv.y, x0, v0b);
    v1a = fmaf(wv.x, x1, v1a); v1b = fmaf(wv.y, x1, v1b);
  }
  {
    float2 bqv = reinterpret_cast<const float2*>(bq)[l];
    float2 bvv = reinterpret_cast<const float2*>(bv)[l];
    q0a += bqv.x; q0b += bqv.y; q1a += bqv.x; q1b += bqv.y;
    v0a += bvv.x; v0b += bvv.y; v1a += bvv.x; v1b += bvv.y;
  }
  {
    int h = l >> 4;           // (2l)>>5
    int d = (2 * l) & 31;
    q_lds[slot0][h * 33 + d] = q0a;
    q_lds[slot0][h * 33 + d + 1] = q0b;
    q_lds[slot1][h * 33 + d] = q1a;
    q_lds[slot1][h * 33 + d + 1] = q1b;
  }
  __syncthreads();

  // ---- qbk[p][i][h] = q[h,:] . bk[i][h*32:...] ----
  if (l < 24) {
    int p = l / 12, g = l % 12;
    int i = g >> 2, h = g & 3;
    int slot = w * 2 + p;
    const float* qp = &q_lds[slot][h * 33];
    const float* bkp = bk + i * 128 + h * 32;
    float s = 0.f;
#pragma unroll 8
    for (int d = 0; d < 32; ++d) s = fmaf(qp[d], bkp[d], s);
    qbk_lds[slot][g] = s;
  }

  // ---- u[p][i][k] = sum_d WkT[i][h_l*32+d][cg*8+k] * q_p[h_l,d] ----
  const int h_l = l >> 4, cg = l & 15;
  float u[2][3][8];
#pragma unroll
  for (int p = 0; p < 2; ++p)
#pragma unroll
    for (int i = 0; i < 3; ++i)
#pragma unroll
      for (int k = 0; k < 8; ++k) u[p][i][k] = 0.f;
  {
    const float* q0p = &q_lds[slot0][h_l * 33];
    const float* q1p = &q_lds[slot1][h_l * 33];
#pragma unroll
    for (int i = 0; i < 3; ++i) {
      const float* wbase = wkT + ((i * 128 + h_l * 32) * 128) + cg * 8;
#pragma unroll 8
      for (int d = 0; d < 32; ++d) {
        float4 wa = *reinterpret_cast<const float4*>(wbase + d * 128);
        float4 wb = *reinterpret_cast<const float4*>(wbase + d * 128 + 4);
        float qv0 = q0p[d], qv1 = q1p[d];
        u[0][i][0] = fmaf(wa.x, qv0, u[0][i][0]);
        u[0][i][1] = fmaf(wa.y, qv0, u[0][i][1]);
        u[0][i][2] = fmaf(wa.z, qv0, u[0][i][2]);
        u[0][i][3] = fmaf(wa.w, qv0, u[0][i][3]);
        u[0][i][4] = fmaf(wb.x, qv0, u[0][i][4]);
        u[0][i][5] = fmaf(wb.y, qv0, u[0][i][5]);
        u[0][i][6] = fmaf(wb.z, qv0, u[0][i][6]);
        u[0][i][7] = fmaf(wb.w, qv0, u[0][i][7]);
        u[1][i][0] = fmaf(wa.x, qv1, u[1][i][0]);
        u[1][i][1] = fmaf(wa.y, qv1, u[1][i][1]);
        u[1][i][2] = fmaf(wa.z, qv1, u[1][i][2]);
        u[1][i][3] = fmaf(wa.w, qv1, u[1][i][3]);
        u[1][i][4] = fmaf(wb.x, qv1, u[1][i][4]);
        u[1][i][5] = fmaf(wb.y, qv1, u[1][i][5]);
        u[1][i][6] = fmaf(wb.z, qv1, u[1][i][6]);
        u[1][i][7] = fmaf(wb.w, qv1, u[1][i][7]);
      }
    }
  }
  __syncthreads();

  // ---- logits + softmax, per point ----
  int nidx0 = (l < 48) ? nbr_idx[(size_t)pt0 * NB_KT + l] : 0;
  int nidx1 = (l < 48) ? nbr_idx[(size_t)pt1 * NB_KT + l] : 0;

  float am_p[2];
#pragma unroll
  for (int p = 0; p < 2; ++p) {
    const int pt = (p == 0) ? pt0 : pt1;
    const int slot = (p == 0) ? slot0 : slot1;
    const int nidx = (p == 0) ? nidx0 : nidx1;
    const float* pcd_b = pcd + (size_t)(pt >> 11) * NB_N * 128;
    float4 sA = *reinterpret_cast<const float4*>(&self_lds[slot][cg * 8]);
    float4 sB = *reinterpret_cast<const float4*>(&self_lds[slot][cg * 8 + 4]);

    int nb0 = __shfl(nidx, 0);
    float2 pre = reinterpret_cast<const float2*>(pcd_b + (size_t)nb0 * 128)[l];

    float lj[3];
#pragma unroll
    for (int i = 0; i < 3; ++i) {
      float qbk_ih = qbk_lds[slot][i * 4 + h_l];
      float myl = 0.f;
      for (int jj = 0; jj < 16; ++jj) {
        int j = i * 16 + jj;
        float2 cur = pre;
        if (j < 47) {  // software-pipeline: prefetch next neighbor row
          int nbn = __shfl(nidx, j + 1);
          pre = reinterpret_cast<const float2*>(pcd_b + (size_t)nbn * 128)[l];
        }
        reinterpret_cast<float2*>(&nbr_lds[w][0])[l] = cur;
        asm volatile("s_waitcnt lgkmcnt(0)" ::: "memory");
        float4 nA = *reinterpret_cast<const float4*>(&nbr_lds[w][cg * 8]);
        float4 nB = *reinterpret_cast<const float4*>(&nbr_lds[w][cg * 8 + 4]);
        float pl;
        pl =      (nA.x - sA.x) * u[p][i][0];
        pl = fmaf((nA.y - sA.y), u[p][i][1], pl);
        pl = fmaf((nA.z - sA.z), u[p][i][2], pl);
        pl = fmaf((nA.w - sA.w), u[p][i][3], pl);
        pl = fmaf((nB.x - sB.x), u[p][i][4], pl);
        pl = fmaf((nB.y - sB.y), u[p][i][5], pl);
        pl = fmaf((nB.z - sB.z), u[p][i][6], pl);
        pl = fmaf((nB.w - sB.w), u[p][i][7], pl);
        // reduce over the 16 lanes of this head-group
        pl += __shfl_xor(pl, 1);
        pl += __shfl_xor(pl, 2);
        pl += __shfl_xor(pl, 4);
        pl += __shfl_xor(pl, 8);
        float lg = (pl + qbk_ih) * INV_SQRT_D;
        if (jj == cg) myl = lg;  // lane cg keeps neighbor j = i*16+cg
      }
      lj[i] = myl;
    }
    // softmax per (i, head-group) across 16 lanes; attn = sum_i sum_k a*logit
    float am = 0.f;
#pragma unroll
    for (int i = 0; i < 3; ++i) {
      float m = lj[i];
      m = fmaxf(m, __shfl_xor(m, 1));
      m = fmaxf(m, __shfl_xor(m, 2));
      m = fmaxf(m, __shfl_xor(m, 4));
      m = fmaxf(m, __shfl_xor(m, 8));
      float e = expf(lj[i] - m);
      float se = e, swl = e * lj[i];
      se += __shfl_xor(se, 1); swl += __shfl_xor(swl, 1);
      se += __shfl_xor(se, 2); swl += __shfl_xor(swl, 2);
      se += __shfl_xor(se, 4); swl += __shfl_xor(swl, 4);
      se += __shfl_xor(se, 8); swl += __shfl_xor(swl, 8);
      am += swl / se;
    }
    am_p[p] = am;  // valid for head h_l on every lane of the group
  }

  // ---- epilogue: out[pt, 2l + {0,1}] = attn[h_l] * v ----
  {
    float2 o0 = make_float2(am_p[0] * v0a, am_p[0] * v0b);
    float2 o1 = make_float2(am_p[1] * v1a, am_p[1] * v1b);
    reinterpret_cast<float2*>(out + (size_t)pt0 * 128)[l] = o0;
    reinterpret_cast<float2*>(out + (size_t)pt1 * 128)[l] = o1;
  }
}

// ---------------------------------------------------------------------------
extern "C" void kernel_launch(void* const* d_in, const int* in_sizes, int n_in,
                              void* d_out, int out_size, void* d_ws, size_t ws_size,
                              hipStream_t stream) {
  const float* pcd   = (const float*)d_in[0];
  const float* coord = (const float*)d_in[1];
  // d_in[2] = K (scalar int, fixed 16 — hardcoded)
  const float* Wq = (const float*)d_in[3];
  const float* bq = (const float*)d_in[4];
  const float* Wk = (const float*)d_in[5];
  const float* bk = (const float*)d_in[6];
  const float* Wv = (const float*)d_in[7];
  const float* bv = (const float*)d_in[8];
  float* out = (float*)d_out;

  // workspace layout
  int*   idx_ws = (int*)d_ws;                                   // 16384*48*4 = 3,145,728 B
  float* sq_ws  = (float*)((char*)d_ws + 3145728);              // 65,536 B
  float* wkT_ws = (float*)((char*)d_ws + 3211264);              // 196,608 B (32B-aligned)

  prep_kernel<<<192, 256, 0, stream>>>(coord, Wk, sq_ws, wkT_ws);
  topk2_kernel<<<NB_B * NB_N / 4, 256, 0, stream>>>(coord, sq_ws, idx_ws);
  main_kernel<<<NB_B * NB_N / 8, 256, 0, stream>>>(pcd, Wq, bq, bk, Wv, bv,
                                                   wkT_ws, idx_ws, out);
}